// Round 3
// baseline (3662.770 us; speedup 1.0000x reference)
//
#include <hip/hip_runtime.h>

#define BB 16
#define LL 512
#define DD 512
#define ROWS (BB*LL)   // 8192

typedef unsigned short u16;

__device__ __forceinline__ float b2f(u16 u) {
    return __uint_as_float(((unsigned int)u) << 16);
}
__device__ __forceinline__ u16 f2b(float f) {
    unsigned int u = __float_as_uint(f);
    u += 0x7FFFu + ((u >> 16) & 1u);
    return (u16)(u >> 16);
}
__device__ __forceinline__ float4 ld4(const void* p, size_t i, int f32) {
    if (f32) return *(const float4*)((const float*)p + i);
    ushort4 q = *(const ushort4*)((const u16*)p + i);
    return make_float4(b2f(q.x), b2f(q.y), b2f(q.z), b2f(q.w));
}
__device__ __forceinline__ float ld1(const void* p, size_t i, int f32) {
    return f32 ? ((const float*)p)[i] : b2f(((const u16*)p)[i]);
}

// Input dtype detector: even-indexed u16s of fp32 data are mantissa garbage ->
// huge bf16 exponents; true-bf16 N(0,1) data never exceeds |v| ~ 2^8.
__global__ void detect(const u16* __restrict__ x, int* __restrict__ flag)
{
    __shared__ int s;
    if (threadIdx.x == 0) s = 0;
    __syncthreads();
    u16 v = x[2 * threadIdx.x] & 0x7FFFu;
    if ((v & 0x7F80u) >= 0x5000u) atomicOr(&s, 1);   // |val| >= 2^33
    __syncthreads();
    if (threadIdx.x == 0) *flag = s;
}

// C[M,N] = act(A[M,K+woff...] @ W[woff + n*K + k]^T + bias[boff+c]).
// W/bias dtype per *flag; A dtype per flag iff amode else bf16.
// accum? Cf+=v : (Cf? Cf=v : Cb=bf16(v)). act:0 none,1 softplus,2 gelu(exact)
__global__ __launch_bounds__(256)
void gemm(const void* __restrict__ A, const void* __restrict__ W, size_t woff,
          float* __restrict__ Cf, u16* __restrict__ Cb,
          int M, int N, int K, int lda,
          const void* __restrict__ bias, size_t boff, int act, int accum, int amode,
          const int* __restrict__ flag)
{
    const int f = *flag;
    const int af = amode ? f : 0;
    __shared__ float As[16][68];
    __shared__ float Ws[16][68];
    const int tid = threadIdx.x;
    const int tx = tid & 15, ty = tid >> 4;
    const int row0 = blockIdx.y * 64;
    const int col0 = blockIdx.x * 64;
    const int lr = tid >> 2;
    const int lc = (tid & 3) * 4;
    float acc[4][4] = {};
    for (int k0 = 0; k0 < K; k0 += 16) {
        float4 av = ld4(A, (size_t)(row0 + lr) * lda + k0 + lc, af);
        float4 wv = ld4(W, woff + (size_t)(col0 + lr) * K + k0 + lc, f);
        As[lc+0][lr] = av.x; As[lc+1][lr] = av.y; As[lc+2][lr] = av.z; As[lc+3][lr] = av.w;
        Ws[lc+0][lr] = wv.x; Ws[lc+1][lr] = wv.y; Ws[lc+2][lr] = wv.z; Ws[lc+3][lr] = wv.w;
        __syncthreads();
        #pragma unroll
        for (int kk = 0; kk < 16; ++kk) {
            float4 a4 = *(const float4*)&As[kk][ty*4];
            float4 w4 = *(const float4*)&Ws[kk][tx*4];
            float a[4] = {a4.x, a4.y, a4.z, a4.w};
            float w[4] = {w4.x, w4.y, w4.z, w4.w};
            #pragma unroll
            for (int i = 0; i < 4; ++i)
                #pragma unroll
                for (int j = 0; j < 4; ++j)
                    acc[i][j] += a[i] * w[j];
        }
        __syncthreads();
    }
    #pragma unroll
    for (int i = 0; i < 4; ++i) {
        int r = row0 + ty*4 + i;
        #pragma unroll
        for (int j = 0; j < 4; ++j) {
            int c = col0 + tx*4 + j;
            float v = acc[i][j];
            if (bias) v += ld1(bias, boff + c, f);
            if (act == 1) v = (v > 15.f) ? v : log1pf(__expf(v));
            else if (act == 2) v = 0.5f * v * (1.f + erff(v * 0.70710678118f));
            size_t o = (size_t)r * N + c;
            if (accum) Cf[o] += v;
            else if (Cf) Cf[o] = v;
            else Cb[o] = f2b(v);
        }
    }
}

__global__ __launch_bounds__(256)
void conv_silu(const u16* __restrict__ xz, const void* __restrict__ cw, size_t cwo,
               const void* __restrict__ cb, size_t cbo, u16* __restrict__ xc, int dsign,
               const int* __restrict__ flag)
{
    const int f = *flag;
    int idx = blockIdx.x * 256 + threadIdx.x;
    if (idx >= ROWS * DD) return;
    int d = idx & (DD - 1);
    int row = idx >> 9;
    int l = row & (LL - 1);
    float xcur = b2f(xz[(size_t)row * 1024 + d]);
    int ln = l + dsign;
    float xnb = (ln >= 0 && ln < LL) ? b2f(xz[(size_t)(row + dsign) * 1024 + d]) : 0.f;
    float v = ld1(cw, cwo + d*2, f) * xnb + ld1(cw, cwo + d*2+1, f) * xcur
            + ld1(cb, cbo + d, f);
    xc[idx] = f2b(v / (1.f + __expf(-v)));
}

__global__ __launch_bounds__(256)
void ssm_scan(const u16* __restrict__ dt, const u16* __restrict__ xc,
              const u16* __restrict__ proj, const u16* __restrict__ xz,
              const void* __restrict__ A_log, size_t ao,
              const void* __restrict__ Dsk, size_t dko,
              u16* __restrict__ g, int rev, const int* __restrict__ flag)
{
    const int f = *flag;
    int lane = threadIdx.x & 15;
    int grp = (blockIdx.x * 256 + threadIdx.x) >> 4;
    int b = grp >> 9;
    int d = grp & 511;
    float Av = -__expf(ld1(A_log, ao + d*16 + lane, f));
    float Dv = ld1(Dsk, dko + d, f);
    float h = 0.f;
    size_t rb = (size_t)b * LL;
    for (int s = 0; s < LL; ++s) {
        int l = rev ? (LL - 1 - s) : s;
        size_t row = rb + l;
        float dtv = b2f(dt[row*512 + d]);
        float xv  = b2f(xc[row*512 + d]);
        float Bn  = b2f(proj[row*64 + 32 + lane]);
        float Cn  = b2f(proj[row*64 + 48 + lane]);
        h = __expf(dtv * Av) * h + dtv * Bn * xv;
        float c = h * Cn;
        c += __shfl_xor(c, 8);
        c += __shfl_xor(c, 4);
        c += __shfl_xor(c, 2);
        c += __shfl_xor(c, 1);
        if (lane == 0) {
            float z = b2f(xz[row*1024 + 512 + d]);
            g[row*512 + d] = f2b((c + Dv * xv) * (z / (1.f + __expf(-z))));
        }
    }
}

// out = LN((Xb?:0)+(Xf?:0))*w[wo+c]+b[bo+c]. omode=1: out dtype per flag (d_out).
__global__ __launch_bounds__(256)
void lnorm(const u16* __restrict__ Xb, const float* __restrict__ Xf,
           const void* __restrict__ w, size_t wo, const void* __restrict__ b, size_t bo,
           void* __restrict__ out, int omode, const int* __restrict__ flag)
{
    const int f = *flag;
    int wid = (blockIdx.x * 256 + threadIdx.x) >> 6;
    int lane = threadIdx.x & 63;
    size_t base = (size_t)wid * DD;
    float v[8];
    float s = 0.f;
    #pragma unroll
    for (int i = 0; i < 8; ++i) {
        int c = lane + i*64;
        float t = 0.f;
        if (Xb) t += b2f(Xb[base + c]);
        if (Xf) t += Xf[base + c];
        v[i] = t; s += t;
    }
    #pragma unroll
    for (int off = 32; off > 0; off >>= 1) s += __shfl_xor(s, off);
    float mean = s * (1.f/512.f);
    float var = 0.f;
    #pragma unroll
    for (int i = 0; i < 8; ++i) { float dlt = v[i] - mean; var += dlt*dlt; }
    #pragma unroll
    for (int off = 32; off > 0; off >>= 1) var += __shfl_xor(var, off);
    float rstd = rsqrtf(var * (1.f/512.f) + 1e-5f);
    #pragma unroll
    for (int i = 0; i < 8; ++i) {
        int c = lane + i*64;
        float o = (v[i] - mean) * rstd * ld1(w, wo + c, f) + ld1(b, bo + c, f);
        if (omode && f) ((float*)out)[base + c] = o;
        else            ((u16*)out)[base + c] = f2b(o);
    }
}

__global__ __launch_bounds__(256)
void acc_init(const void* __restrict__ x, float* __restrict__ o, int n, int amode,
              const int* __restrict__ flag)
{
    const int f = amode ? *flag : 0;
    int i = blockIdx.x * 256 + threadIdx.x;
    if (i < n) o[i] = ld1(x, i, f);
}

extern "C" void kernel_launch(void* const* d_in, const int* in_sizes, int n_in,
                              void* d_out, int out_size, void* d_ws, size_t ws_size,
                              hipStream_t stream)
{
    (void)in_sizes; (void)n_in; (void)out_size; (void)ws_size;
    const void* X       = d_in[0];
    const void* in_w    = d_in[1];
    const void* conv_w  = d_in[2];
    const void* conv_b  = d_in[3];
    const void* xproj_w = d_in[4];
    const void* dt_w    = d_in[5];
    const void* dt_b    = d_in[6];
    const void* A_log   = d_in[7];
    const void* D_skip  = d_in[8];
    const void* out_w   = d_in[9];
    const void* ffn1_w  = d_in[10];
    const void* ffn1_b  = d_in[11];
    const void* ffn2_w  = d_in[12];
    const void* ffn2_b  = d_in[13];
    const void* n1_w    = d_in[14];
    const void* n1_b    = d_in[15];
    const void* n2_w    = d_in[16];
    const void* n2_b    = d_in[17];
    const void* fn_w    = d_in[18];
    const void* fn_b    = d_in[19];

    char* p = (char*)d_ws;
    float* acc  = (float*)(p);
    u16*   cur  = (u16*)(p + 16777216);
    u16*   xz   = (u16*)(p + 25165824);
    u16*   xc   = (u16*)(p + 41943040);
    u16*   dtg  = (u16*)(p + 50331648);
    u16*   proj = (u16*)(p + 58720256);
    u16*   ffh  = (u16*)(p);
    float* y2   = (float*)(p + 33554432);
    u16*   x1   = (u16*)(p + 50331648);
    int*   flag = (int*)(p + 59768832);

    detect<<<1, 512, 0, stream>>>((const u16*)X, flag);

    for (int e = 0; e < 2; ++e) {
        int amode = (e == 0) ? 1 : 0;
        const void* inp = (e == 0) ? X : (const void*)cur;
        acc_init<<<ROWS*DD/256, 256, 0, stream>>>(inp, acc, ROWS*DD, amode, flag);
        for (int dir = 0; dir < 2; ++dir) {
            size_t ed = (size_t)(e*2 + dir);
            gemm<<<dim3(16,128), 256, 0, stream>>>(
                inp, in_w, ed*1024*512, nullptr, xz,
                ROWS, 1024, 512, 512, nullptr, 0, 0, 0, amode, flag);
            conv_silu<<<ROWS*DD/256, 256, 0, stream>>>(
                xz, conv_w, ed*1024, conv_b, ed*512, xc, dir ? 1 : -1, flag);
            gemm<<<dim3(1,128), 256, 0, stream>>>(
                xc, xproj_w, ed*64*512, nullptr, proj,
                ROWS, 64, 512, 512, nullptr, 0, 0, 0, 0, flag);
            gemm<<<dim3(8,128), 256, 0, stream>>>(
                proj, dt_w, ed*512*32, nullptr, dtg,
                ROWS, 512, 32, 64, dt_b, ed*512, 1, 0, 0, flag);
            ssm_scan<<<512, 256, 0, stream>>>(
                dtg, xc, proj, xz, A_log, ed*512*16, D_skip, ed*512, dtg, dir, flag);
            gemm<<<dim3(8,128), 256, 0, stream>>>(
                dtg, out_w, ed*512*512, acc, nullptr,
                ROWS, 512, 512, 512, nullptr, 0, 0, 1, 0, flag);
        }
        size_t eo = (size_t)e * 512;
        lnorm<<<2048, 256, 0, stream>>>(nullptr, acc, n1_w, eo, n1_b, eo, x1, 0, flag);
        gemm<<<dim3(32,128), 256, 0, stream>>>(
            x1, ffn1_w, (size_t)e*2048*512, nullptr, ffh,
            ROWS, 2048, 512, 512, ffn1_b, (size_t)e*2048, 2, 0, 0, flag);
        gemm<<<dim3(8,128), 256, 0, stream>>>(
            ffh, ffn2_w, (size_t)e*512*2048, y2, nullptr,
            ROWS, 512, 2048, 2048, ffn2_b, eo, 0, 0, 0, flag);
        lnorm<<<2048, 256, 0, stream>>>(x1, y2, n2_w, eo, n2_b, eo, cur, 0, flag);
    }
    lnorm<<<2048, 256, 0, stream>>>(cur, nullptr, fn_w, 0, fn_b, 0, d_out, 1, flag);
}

// Round 4
// 2665.235 us; speedup vs baseline: 1.3743x; 1.3743x over previous
//
#include <hip/hip_runtime.h>

#define BB 16
#define LL 512
#define DD 512
#define ROWS (BB*LL)   // 8192

typedef unsigned short u16;

__device__ __forceinline__ float b2f(u16 u) {
    return __uint_as_float(((unsigned int)u) << 16);
}
__device__ __forceinline__ u16 f2b(float f) {
    unsigned int u = __float_as_uint(f);
    u += 0x7FFFu + ((u >> 16) & 1u);
    return (u16)(u >> 16);
}
__device__ __forceinline__ float4 ld4(const void* p, size_t i, int f32) {
    if (f32) return *(const float4*)((const float*)p + i);
    ushort4 q = *(const ushort4*)((const u16*)p + i);
    return make_float4(b2f(q.x), b2f(q.y), b2f(q.z), b2f(q.w));
}
__device__ __forceinline__ float ld1(const void* p, size_t i, int f32) {
    return f32 ? ((const float*)p)[i] : b2f(((const u16*)p)[i]);
}

// Input dtype detector: even-indexed u16s of fp32 data are mantissa garbage ->
// huge bf16 exponents; true-bf16 N(0,1) data never exceeds |v| ~ 2^8.
__global__ void detect(const u16* __restrict__ x, int* __restrict__ flag)
{
    __shared__ int s;
    if (threadIdx.x == 0) s = 0;
    __syncthreads();
    u16 v = x[2 * threadIdx.x] & 0x7FFFu;
    if ((v & 0x7F80u) >= 0x5000u) atomicOr(&s, 1);   // |val| >= 2^33
    __syncthreads();
    if (threadIdx.x == 0) *flag = s;
}

// C[M,N] = act(A[M,K] @ W[woff + n*K + k]^T + bias[boff+c]).
// W/bias dtype per *flag; A dtype per flag iff amode else bf16.
// accum? Cf+=v : (Cf? Cf=v : Cb=bf16(v)). act:0 none,1 softplus,2 gelu(exact)
__global__ __launch_bounds__(256)
void gemm(const void* __restrict__ A, const void* __restrict__ W, size_t woff,
          float* __restrict__ Cf, u16* __restrict__ Cb,
          int M, int N, int K, int lda,
          const void* __restrict__ bias, size_t boff, int act, int accum, int amode,
          const int* __restrict__ flag)
{
    const int f = *flag;
    const int af = amode ? f : 0;
    __shared__ float As[16][68];
    __shared__ float Ws[16][68];
    const int tid = threadIdx.x;
    const int tx = tid & 15, ty = tid >> 4;
    const int row0 = blockIdx.y * 64;
    const int col0 = blockIdx.x * 64;
    const int lr = tid >> 2;
    const int lc = (tid & 3) * 4;
    float acc[4][4] = {};
    for (int k0 = 0; k0 < K; k0 += 16) {
        float4 av = ld4(A, (size_t)(row0 + lr) * lda + k0 + lc, af);
        float4 wv = ld4(W, woff + (size_t)(col0 + lr) * K + k0 + lc, f);
        As[lc+0][lr] = av.x; As[lc+1][lr] = av.y; As[lc+2][lr] = av.z; As[lc+3][lr] = av.w;
        Ws[lc+0][lr] = wv.x; Ws[lc+1][lr] = wv.y; Ws[lc+2][lr] = wv.z; Ws[lc+3][lr] = wv.w;
        __syncthreads();
        #pragma unroll
        for (int kk = 0; kk < 16; ++kk) {
            float4 a4 = *(const float4*)&As[kk][ty*4];
            float4 w4 = *(const float4*)&Ws[kk][tx*4];
            float a[4] = {a4.x, a4.y, a4.z, a4.w};
            float w[4] = {w4.x, w4.y, w4.z, w4.w};
            #pragma unroll
            for (int i = 0; i < 4; ++i)
                #pragma unroll
                for (int j = 0; j < 4; ++j)
                    acc[i][j] += a[i] * w[j];
        }
        __syncthreads();
    }
    #pragma unroll
    for (int i = 0; i < 4; ++i) {
        int r = row0 + ty*4 + i;
        #pragma unroll
        for (int j = 0; j < 4; ++j) {
            int c = col0 + tx*4 + j;
            float v = acc[i][j];
            if (bias) v += ld1(bias, boff + c, f);
            if (act == 1) v = (v > 15.f) ? v : log1pf(__expf(v));
            else if (act == 2) v = 0.5f * v * (1.f + erff(v * 0.70710678118f));
            size_t o = (size_t)r * N + c;
            if (accum) Cf[o] += v;
            else if (Cf) Cf[o] = v;
            else Cb[o] = f2b(v);
        }
    }
}

__global__ __launch_bounds__(256)
void conv_silu(const u16* __restrict__ xz, const void* __restrict__ cw, size_t cwo,
               const void* __restrict__ cb, size_t cbo, u16* __restrict__ xc, int dsign,
               const int* __restrict__ flag)
{
    const int f = *flag;
    int idx = blockIdx.x * 256 + threadIdx.x;
    if (idx >= ROWS * DD) return;
    int d = idx & (DD - 1);
    int row = idx >> 9;
    int l = row & (LL - 1);
    float xcur = b2f(xz[(size_t)row * 1024 + d]);
    int ln = l + dsign;
    float xnb = (ln >= 0 && ln < LL) ? b2f(xz[(size_t)(row + dsign) * 1024 + d]) : 0.f;
    float v = ld1(cw, cwo + d*2, f) * xnb + ld1(cw, cwo + d*2+1, f) * xcur
            + ld1(cb, cbo + d, f);
    xc[idx] = f2b(v / (1.f + __expf(-v)));
}

// Selective scan, 8-step register-prefetch chunks. 16 lanes per (b,d), one per n.
// Loads for a chunk are issued before its compute; only h is loop-carried, so one
// memory-latency stall is amortized over 8 steps. g aliases dt only at identical
// (row,d) and each chunk's loads precede its stores in program order -> safe.
__global__ __launch_bounds__(256)
void ssm_scan(const u16* __restrict__ dt, const u16* __restrict__ xc,
              const u16* __restrict__ proj, const u16* __restrict__ xz,
              const void* __restrict__ A_log, size_t ao,
              const void* __restrict__ Dsk, size_t dko,
              u16* __restrict__ g, int rev, const int* __restrict__ flag)
{
    const int f = *flag;
    int lane = threadIdx.x & 15;
    int grp = (blockIdx.x * 256 + threadIdx.x) >> 4;
    int b = grp >> 9;
    int d = grp & 511;
    float Av = -__expf(ld1(A_log, ao + d*16 + lane, f));
    float Dv = ld1(Dsk, dko + d, f);
    float h = 0.f;
    size_t rb = (size_t)b * LL;
    for (int s0 = 0; s0 < LL; s0 += 8) {
        float dtv[8], xv[8], Bn[8], Cn[8], zz[8];
        #pragma unroll
        for (int j = 0; j < 8; ++j) {
            int l = rev ? (LL - 1 - (s0 + j)) : (s0 + j);
            size_t row = rb + l;
            dtv[j] = b2f(dt[row*512 + d]);
            xv[j]  = b2f(xc[row*512 + d]);
            Bn[j]  = b2f(proj[row*64 + 32 + lane]);
            Cn[j]  = b2f(proj[row*64 + 48 + lane]);
            zz[j]  = b2f(xz[row*1024 + 512 + d]);
        }
        #pragma unroll
        for (int j = 0; j < 8; ++j) {
            int l = rev ? (LL - 1 - (s0 + j)) : (s0 + j);
            size_t row = rb + l;
            h = __expf(dtv[j] * Av) * h + dtv[j] * Bn[j] * xv[j];
            float c = h * Cn[j];
            c += __shfl_xor(c, 8);
            c += __shfl_xor(c, 4);
            c += __shfl_xor(c, 2);
            c += __shfl_xor(c, 1);
            if (lane == 0) {
                float zs = zz[j] / (1.f + __expf(-zz[j]));
                g[row*512 + d] = f2b((c + Dv * xv[j]) * zs);
            }
        }
    }
}

// out = LN((Xb?:0)+(Xf?:0))*w[wo+c]+b[bo+c]. omode=1: out dtype per flag (d_out).
__global__ __launch_bounds__(256)
void lnorm(const u16* __restrict__ Xb, const float* __restrict__ Xf,
           const void* __restrict__ w, size_t wo, const void* __restrict__ b, size_t bo,
           void* __restrict__ out, int omode, const int* __restrict__ flag)
{
    const int f = *flag;
    int wid = (blockIdx.x * 256 + threadIdx.x) >> 6;
    int lane = threadIdx.x & 63;
    size_t base = (size_t)wid * DD;
    float v[8];
    float s = 0.f;
    #pragma unroll
    for (int i = 0; i < 8; ++i) {
        int c = lane + i*64;
        float t = 0.f;
        if (Xb) t += b2f(Xb[base + c]);
        if (Xf) t += Xf[base + c];
        v[i] = t; s += t;
    }
    #pragma unroll
    for (int off = 32; off > 0; off >>= 1) s += __shfl_xor(s, off);
    float mean = s * (1.f/512.f);
    float var = 0.f;
    #pragma unroll
    for (int i = 0; i < 8; ++i) { float dlt = v[i] - mean; var += dlt*dlt; }
    #pragma unroll
    for (int off = 32; off > 0; off >>= 1) var += __shfl_xor(var, off);
    float rstd = rsqrtf(var * (1.f/512.f) + 1e-5f);
    #pragma unroll
    for (int i = 0; i < 8; ++i) {
        int c = lane + i*64;
        float o = (v[i] - mean) * rstd * ld1(w, wo + c, f) + ld1(b, bo + c, f);
        if (omode && f) ((float*)out)[base + c] = o;
        else            ((u16*)out)[base + c] = f2b(o);
    }
}

__global__ __launch_bounds__(256)
void acc_init(const void* __restrict__ x, float* __restrict__ o, int n, int amode,
              const int* __restrict__ flag)
{
    const int f = amode ? *flag : 0;
    int i = blockIdx.x * 256 + threadIdx.x;
    if (i < n) o[i] = ld1(x, i, f);
}

extern "C" void kernel_launch(void* const* d_in, const int* in_sizes, int n_in,
                              void* d_out, int out_size, void* d_ws, size_t ws_size,
                              hipStream_t stream)
{
    (void)in_sizes; (void)n_in; (void)out_size; (void)ws_size;
    const void* X       = d_in[0];
    const void* in_w    = d_in[1];
    const void* conv_w  = d_in[2];
    const void* conv_b  = d_in[3];
    const void* xproj_w = d_in[4];
    const void* dt_w    = d_in[5];
    const void* dt_b    = d_in[6];
    const void* A_log   = d_in[7];
    const void* D_skip  = d_in[8];
    const void* out_w   = d_in[9];
    const void* ffn1_w  = d_in[10];
    const void* ffn1_b  = d_in[11];
    const void* ffn2_w  = d_in[12];
    const void* ffn2_b  = d_in[13];
    const void* n1_w    = d_in[14];
    const void* n1_b    = d_in[15];
    const void* n2_w    = d_in[16];
    const void* n2_b    = d_in[17];
    const void* fn_w    = d_in[18];
    const void* fn_b    = d_in[19];

    char* p = (char*)d_ws;
    float* acc  = (float*)(p);
    u16*   cur  = (u16*)(p + 16777216);
    u16*   xz   = (u16*)(p + 25165824);
    u16*   xc   = (u16*)(p + 41943040);
    u16*   dtg  = (u16*)(p + 50331648);
    u16*   proj = (u16*)(p + 58720256);
    u16*   ffh  = (u16*)(p);
    float* y2   = (float*)(p + 33554432);
    u16*   x1   = (u16*)(p + 50331648);
    int*   flag = (int*)(p + 59768832);

    detect<<<1, 512, 0, stream>>>((const u16*)X, flag);

    for (int e = 0; e < 2; ++e) {
        int amode = (e == 0) ? 1 : 0;
        const void* inp = (e == 0) ? X : (const void*)cur;
        acc_init<<<ROWS*DD/256, 256, 0, stream>>>(inp, acc, ROWS*DD, amode, flag);
        for (int dir = 0; dir < 2; ++dir) {
            size_t ed = (size_t)(e*2 + dir);
            gemm<<<dim3(16,128), 256, 0, stream>>>(
                inp, in_w, ed*1024*512, nullptr, xz,
                ROWS, 1024, 512, 512, nullptr, 0, 0, 0, amode, flag);
            conv_silu<<<ROWS*DD/256, 256, 0, stream>>>(
                xz, conv_w, ed*1024, conv_b, ed*512, xc, dir ? 1 : -1, flag);
            gemm<<<dim3(1,128), 256, 0, stream>>>(
                xc, xproj_w, ed*64*512, nullptr, proj,
                ROWS, 64, 512, 512, nullptr, 0, 0, 0, 0, flag);
            gemm<<<dim3(8,128), 256, 0, stream>>>(
                proj, dt_w, ed*512*32, nullptr, dtg,
                ROWS, 512, 32, 64, dt_b, ed*512, 1, 0, 0, flag);
            ssm_scan<<<512, 256, 0, stream>>>(
                dtg, xc, proj, xz, A_log, ed*512*16, D_skip, ed*512, dtg, dir, flag);
            gemm<<<dim3(8,128), 256, 0, stream>>>(
                dtg, out_w, ed*512*512, acc, nullptr,
                ROWS, 512, 512, 512, nullptr, 0, 0, 1, 0, flag);
        }
        size_t eo = (size_t)e * 512;
        lnorm<<<2048, 256, 0, stream>>>(nullptr, acc, n1_w, eo, n1_b, eo, x1, 0, flag);
        gemm<<<dim3(32,128), 256, 0, stream>>>(
            x1, ffn1_w, (size_t)e*2048*512, nullptr, ffh,
            ROWS, 2048, 512, 512, ffn1_b, (size_t)e*2048, 2, 0, 0, flag);
        gemm<<<dim3(8,128), 256, 0, stream>>>(
            ffh, ffn2_w, (size_t)e*512*2048, y2, nullptr,
            ROWS, 512, 2048, 2048, ffn2_b, eo, 0, 0, 0, flag);
        lnorm<<<2048, 256, 0, stream>>>(x1, y2, n2_w, eo, n2_b, eo, cur, 0, flag);
    }
    lnorm<<<2048, 256, 0, stream>>>(cur, nullptr, fn_w, 0, fn_b, 0, d_out, 1, flag);
}

// Round 5
// 1586.284 us; speedup vs baseline: 2.3090x; 1.6802x over previous
//
#include <hip/hip_runtime.h>

#define BB 16
#define LL 512
#define DD 512
#define ROWS (BB*LL)   // 8192

typedef unsigned short u16;
typedef __attribute__((ext_vector_type(8))) short short8;
typedef __attribute__((ext_vector_type(4))) float f32x4;

__device__ __forceinline__ float b2f(u16 u) {
    return __uint_as_float(((unsigned int)u) << 16);
}
__device__ __forceinline__ u16 f2b(float f) {
    unsigned int u = __float_as_uint(f);
    u += 0x7FFFu + ((u >> 16) & 1u);
    return (u16)(u >> 16);
}
__device__ __forceinline__ float4 ld4(const void* p, size_t i, int f32) {
    if (f32) return *(const float4*)((const float*)p + i);
    ushort4 q = *(const ushort4*)((const u16*)p + i);
    return make_float4(b2f(q.x), b2f(q.y), b2f(q.z), b2f(q.w));
}
__device__ __forceinline__ float ld1(const void* p, size_t i, int f32) {
    return f32 ? ((const float*)p)[i] : b2f(((const u16*)p)[i]);
}

// Input dtype detector (fp32 vs bf16), see R2 notes.
__global__ void detect(const u16* __restrict__ x, int* __restrict__ flag)
{
    __shared__ int s;
    if (threadIdx.x == 0) s = 0;
    __syncthreads();
    u16 v = x[2 * threadIdx.x] & 0x7FFFu;
    if ((v & 0x7F80u) >= 0x5000u) atomicOr(&s, 1);
    __syncthreads();
    if (threadIdx.x == 0) *flag = s;
}

// Convert X + 6 weight tensors to one contiguous bf16 region (element counts fixed).
__global__ __launch_bounds__(256)
void cvt_all(const void* __restrict__ s0, const void* __restrict__ s1,
             const void* __restrict__ s2, const void* __restrict__ s3,
             const void* __restrict__ s4, const void* __restrict__ s5,
             const void* __restrict__ s6, u16* __restrict__ dst,
             const int* __restrict__ flag)
{
    const int f = *flag;
    size_t i = (size_t)blockIdx.x * 256 + threadIdx.x;
    if (i >= 11730944u) return;
    float v;
    if      (i <  4194304u) v = ld1(s0, i, f);
    else if (i <  6291456u) v = ld1(s1, i - 4194304u, f);
    else if (i <  6422528u) v = ld1(s2, i - 6291456u, f);
    else if (i <  6488064u) v = ld1(s3, i - 6422528u, f);
    else if (i <  7536640u) v = ld1(s4, i - 6488064u, f);
    else if (i <  9633792u) v = ld1(s5, i - 7536640u, f);
    else                    v = ld1(s6, i - 9633792u, f);
    dst[i] = f2b(v);
}

// MFMA GEMM: C[M,N] = act(A[M,K] @ W[N,K]^T + bias). A,W bf16 row-major.
// 128x128 block tile, 4 waves (64x64 each, 4x4 MFMA grid), BK=32.
// LDS stride 56 elems (112 B): 16B-aligned, <=2-way bank aliasing.
// accum? Cf+=v : (Cf? Cf=v : Cb=bf16(v)). act:0 none,2 gelu(exact)
__global__ __launch_bounds__(256)
void gemm_mfma(const u16* __restrict__ A, const u16* __restrict__ W,
               float* __restrict__ Cf, u16* __restrict__ Cb,
               int M, int N, int K,
               const void* __restrict__ bias, size_t boff, int act, int accum,
               const int* __restrict__ flag)
{
    const int f = *flag;
    __shared__ u16 As[128][56];
    __shared__ u16 Ws[128][56];
    const int tid  = threadIdx.x;
    const int lane = tid & 63;
    const int wid  = tid >> 6;
    const int wr   = (wid >> 1) * 64;
    const int wc   = (wid & 1) * 64;
    const int row0 = blockIdx.y * 128;
    const int col0 = blockIdx.x * 128;
    const int sr = tid >> 1;            // staging row 0..127
    const int sc = (tid & 1) * 16;      // staging col 0 or 16

    const int mrow = lane & 15;         // fragment row within 16
    const int kq   = (lane >> 4) * 8;   // fragment k-offset within 32

    f32x4 acc[4][4] = {};
    for (int k0 = 0; k0 < K; k0 += 32) {
        const uint4* ga = (const uint4*)(A + (size_t)(row0 + sr) * K + k0 + sc);
        const uint4* gw = (const uint4*)(W + (size_t)(col0 + sr) * K + k0 + sc);
        uint4 a0 = ga[0], a1 = ga[1];
        uint4 w0 = gw[0], w1 = gw[1];
        *(uint4*)&As[sr][sc]     = a0;
        *(uint4*)&As[sr][sc + 8] = a1;
        *(uint4*)&Ws[sr][sc]     = w0;
        *(uint4*)&Ws[sr][sc + 8] = w1;
        __syncthreads();
        short8 af[4], bf[4];
        #pragma unroll
        for (int mi = 0; mi < 4; ++mi)
            af[mi] = *(const short8*)&As[wr + mi*16 + mrow][kq];
        #pragma unroll
        for (int ni = 0; ni < 4; ++ni)
            bf[ni] = *(const short8*)&Ws[wc + ni*16 + mrow][kq];
        #pragma unroll
        for (int mi = 0; mi < 4; ++mi)
            #pragma unroll
            for (int ni = 0; ni < 4; ++ni)
                acc[mi][ni] = __builtin_amdgcn_mfma_f32_16x16x32_bf16(
                    af[mi], bf[ni], acc[mi][ni], 0, 0, 0);
        __syncthreads();
    }
    // D layout: row=(lane>>4)*4+reg, col=lane&15
    const int drow = (lane >> 4) * 4;
    const int dcol = lane & 15;
    #pragma unroll
    for (int mi = 0; mi < 4; ++mi) {
        #pragma unroll
        for (int ni = 0; ni < 4; ++ni) {
            #pragma unroll
            for (int r = 0; r < 4; ++r) {
                int row = row0 + wr + mi*16 + drow + r;
                int col = col0 + wc + ni*16 + dcol;
                float v = acc[mi][ni][r];
                if (bias) v += ld1(bias, boff + col, f);
                if (act == 2) v = 0.5f * v * (1.f + erff(v * 0.70710678118f));
                size_t o = (size_t)row * N + col;
                if (accum) Cf[o] += v;
                else if (Cf) Cf[o] = v;
                else Cb[o] = f2b(v);
            }
        }
    }
}

// VALU GEMM (kept for small shapes: xproj N=64, dt K=32).
__global__ __launch_bounds__(256)
void gemm(const void* __restrict__ A, const void* __restrict__ W, size_t woff,
          float* __restrict__ Cf, u16* __restrict__ Cb,
          int M, int N, int K, int lda,
          const void* __restrict__ bias, size_t boff, int act, int accum, int amode,
          const int* __restrict__ flag)
{
    const int f = *flag;
    const int af = amode ? f : 0;
    __shared__ float As[16][68];
    __shared__ float Ws[16][68];
    const int tid = threadIdx.x;
    const int tx = tid & 15, ty = tid >> 4;
    const int row0 = blockIdx.y * 64;
    const int col0 = blockIdx.x * 64;
    const int lr = tid >> 2;
    const int lc = (tid & 3) * 4;
    float acc[4][4] = {};
    for (int k0 = 0; k0 < K; k0 += 16) {
        float4 av = ld4(A, (size_t)(row0 + lr) * lda + k0 + lc, af);
        float4 wv = ld4(W, woff + (size_t)(col0 + lr) * K + k0 + lc, f);
        As[lc+0][lr] = av.x; As[lc+1][lr] = av.y; As[lc+2][lr] = av.z; As[lc+3][lr] = av.w;
        Ws[lc+0][lr] = wv.x; Ws[lc+1][lr] = wv.y; Ws[lc+2][lr] = wv.z; Ws[lc+3][lr] = wv.w;
        __syncthreads();
        #pragma unroll
        for (int kk = 0; kk < 16; ++kk) {
            float4 a4 = *(const float4*)&As[kk][ty*4];
            float4 w4 = *(const float4*)&Ws[kk][tx*4];
            float a[4] = {a4.x, a4.y, a4.z, a4.w};
            float w[4] = {w4.x, w4.y, w4.z, w4.w};
            #pragma unroll
            for (int i = 0; i < 4; ++i)
                #pragma unroll
                for (int j = 0; j < 4; ++j)
                    acc[i][j] += a[i] * w[j];
        }
        __syncthreads();
    }
    #pragma unroll
    for (int i = 0; i < 4; ++i) {
        int r = row0 + ty*4 + i;
        #pragma unroll
        for (int j = 0; j < 4; ++j) {
            int c = col0 + tx*4 + j;
            float v = acc[i][j];
            if (bias) v += ld1(bias, boff + c, f);
            if (act == 1) v = (v > 15.f) ? v : log1pf(__expf(v));
            else if (act == 2) v = 0.5f * v * (1.f + erff(v * 0.70710678118f));
            size_t o = (size_t)r * N + c;
            if (accum) Cf[o] += v;
            else if (Cf) Cf[o] = v;
            else Cb[o] = f2b(v);
        }
    }
}

__global__ __launch_bounds__(256)
void conv_silu(const u16* __restrict__ xz, const void* __restrict__ cw, size_t cwo,
               const void* __restrict__ cb, size_t cbo, u16* __restrict__ xc, int dsign,
               const int* __restrict__ flag)
{
    const int f = *flag;
    int idx = blockIdx.x * 256 + threadIdx.x;
    if (idx >= ROWS * DD) return;
    int d = idx & (DD - 1);
    int row = idx >> 9;
    int l = row & (LL - 1);
    float xcur = b2f(xz[(size_t)row * 1024 + d]);
    int ln = l + dsign;
    float xnb = (ln >= 0 && ln < LL) ? b2f(xz[(size_t)(row + dsign) * 1024 + d]) : 0.f;
    float v = ld1(cw, cwo + d*2, f) * xnb + ld1(cw, cwo + d*2+1, f) * xcur
            + ld1(cb, cbo + d, f);
    xc[idx] = f2b(v / (1.f + __expf(-v)));
}

// Selective scan, 8-step register-prefetch chunks (see R3 notes).
__global__ __launch_bounds__(256)
void ssm_scan(const u16* __restrict__ dt, const u16* __restrict__ xc,
              const u16* __restrict__ proj, const u16* __restrict__ xz,
              const void* __restrict__ A_log, size_t ao,
              const void* __restrict__ Dsk, size_t dko,
              u16* __restrict__ g, int rev, const int* __restrict__ flag)
{
    const int f = *flag;
    int lane = threadIdx.x & 15;
    int grp = (blockIdx.x * 256 + threadIdx.x) >> 4;
    int b = grp >> 9;
    int d = grp & 511;
    float Av = -__expf(ld1(A_log, ao + d*16 + lane, f));
    float Dv = ld1(Dsk, dko + d, f);
    float h = 0.f;
    size_t rb = (size_t)b * LL;
    for (int s0 = 0; s0 < LL; s0 += 8) {
        float dtv[8], xv[8], Bn[8], Cn[8], zz[8];
        #pragma unroll
        for (int j = 0; j < 8; ++j) {
            int l = rev ? (LL - 1 - (s0 + j)) : (s0 + j);
            size_t row = rb + l;
            dtv[j] = b2f(dt[row*512 + d]);
            xv[j]  = b2f(xc[row*512 + d]);
            Bn[j]  = b2f(proj[row*64 + 32 + lane]);
            Cn[j]  = b2f(proj[row*64 + 48 + lane]);
            zz[j]  = b2f(xz[row*1024 + 512 + d]);
        }
        #pragma unroll
        for (int j = 0; j < 8; ++j) {
            int l = rev ? (LL - 1 - (s0 + j)) : (s0 + j);
            size_t row = rb + l;
            h = __expf(dtv[j] * Av) * h + dtv[j] * Bn[j] * xv[j];
            float c = h * Cn[j];
            c += __shfl_xor(c, 8);
            c += __shfl_xor(c, 4);
            c += __shfl_xor(c, 2);
            c += __shfl_xor(c, 1);
            if (lane == 0) {
                float zs = zz[j] / (1.f + __expf(-zz[j]));
                g[row*512 + d] = f2b((c + Dv * xv[j]) * zs);
            }
        }
    }
}

__global__ __launch_bounds__(256)
void lnorm(const u16* __restrict__ Xb, const float* __restrict__ Xf,
           const void* __restrict__ w, size_t wo, const void* __restrict__ b, size_t bo,
           void* __restrict__ out, int omode, const int* __restrict__ flag)
{
    const int f = *flag;
    int wid = (blockIdx.x * 256 + threadIdx.x) >> 6;
    int lane = threadIdx.x & 63;
    size_t base = (size_t)wid * DD;
    float v[8];
    float s = 0.f;
    #pragma unroll
    for (int i = 0; i < 8; ++i) {
        int c = lane + i*64;
        float t = 0.f;
        if (Xb) t += b2f(Xb[base + c]);
        if (Xf) t += Xf[base + c];
        v[i] = t; s += t;
    }
    #pragma unroll
    for (int off = 32; off > 0; off >>= 1) s += __shfl_xor(s, off);
    float mean = s * (1.f/512.f);
    float var = 0.f;
    #pragma unroll
    for (int i = 0; i < 8; ++i) { float dlt = v[i] - mean; var += dlt*dlt; }
    #pragma unroll
    for (int off = 32; off > 0; off >>= 1) var += __shfl_xor(var, off);
    float rstd = rsqrtf(var * (1.f/512.f) + 1e-5f);
    #pragma unroll
    for (int i = 0; i < 8; ++i) {
        int c = lane + i*64;
        float o = (v[i] - mean) * rstd * ld1(w, wo + c, f) + ld1(b, bo + c, f);
        if (omode && f) ((float*)out)[base + c] = o;
        else            ((u16*)out)[base + c] = f2b(o);
    }
}

__global__ __launch_bounds__(256)
void acc_init(const void* __restrict__ x, float* __restrict__ o, int n, int amode,
              const int* __restrict__ flag)
{
    const int f = amode ? *flag : 0;
    int i = blockIdx.x * 256 + threadIdx.x;
    if (i < n) o[i] = ld1(x, i, f);
}

extern "C" void kernel_launch(void* const* d_in, const int* in_sizes, int n_in,
                              void* d_out, int out_size, void* d_ws, size_t ws_size,
                              hipStream_t stream)
{
    (void)in_sizes; (void)n_in; (void)out_size; (void)ws_size;
    const void* X       = d_in[0];
    const void* in_w    = d_in[1];
    const void* conv_w  = d_in[2];
    const void* conv_b  = d_in[3];
    const void* xproj_w = d_in[4];
    const void* dt_w    = d_in[5];
    const void* dt_b    = d_in[6];
    const void* A_log   = d_in[7];
    const void* D_skip  = d_in[8];
    const void* out_w   = d_in[9];
    const void* ffn1_w  = d_in[10];
    const void* ffn1_b  = d_in[11];
    const void* ffn2_w  = d_in[12];
    const void* ffn2_b  = d_in[13];
    const void* n1_w    = d_in[14];
    const void* n1_b    = d_in[15];
    const void* n2_w    = d_in[16];
    const void* n2_b    = d_in[17];
    const void* fn_w    = d_in[18];
    const void* fn_b    = d_in[19];

    // Workspace: mamba phase: acc f32 @0 (16M) | cur bf16 @16M (8M) | xz @24M (16M)
    //  | xc @40M (8M) | dtg @48M (8M) | proj @56M (1M) | flag @57M
    // ffn phase: ffh @0 (32M) | y2 f32 @32M (16M) | x1 @48M (8M)
    // persistent bf16: xin @58M (8M) | wbf @66M (14.4M)  -> total ~80.4 MB
    char* p = (char*)d_ws;
    float* acc  = (float*)(p);
    u16*   cur  = (u16*)(p + 16777216);
    u16*   xz   = (u16*)(p + 25165824);
    u16*   xc   = (u16*)(p + 41943040);
    u16*   dtg  = (u16*)(p + 50331648);
    u16*   proj = (u16*)(p + 58720256);
    int*   flag = (int*)(p + 59768832);
    u16*   ffh  = (u16*)(p);
    float* y2   = (float*)(p + 33554432);
    u16*   x1   = (u16*)(p + 50331648);
    u16*   xin  = (u16*)(p + 60817408);
    u16*   wbf  = xin + 4194304;          // weights bf16, contiguous after xin
    // wbf element offsets:
    const size_t W_INW = 0,       W_XPJ = 2097152, W_DTW = 2228224;
    const size_t W_OUT = 2293760, W_FF1 = 3342336, W_FF2 = 5439488;
    (void)W_XPJ; (void)W_DTW;

    detect<<<1, 512, 0, stream>>>((const u16*)X, flag);
    cvt_all<<<(11730944 + 255)/256, 256, 0, stream>>>(
        X, in_w, xproj_w, dt_w, out_w, ffn1_w, ffn2_w, xin, flag);

    for (int e = 0; e < 2; ++e) {
        int amode = (e == 0) ? 1 : 0;
        const void* inp  = (e == 0) ? X : (const void*)cur;
        const u16*  inpb = (e == 0) ? xin : cur;
        acc_init<<<ROWS*DD/256, 256, 0, stream>>>(inp, acc, ROWS*DD, amode, flag);
        for (int dir = 0; dir < 2; ++dir) {
            size_t ed = (size_t)(e*2 + dir);
            // xz = inp @ in_w[ed]^T : [8192,1024]
            gemm_mfma<<<dim3(8,64), 256, 0, stream>>>(
                inpb, wbf + W_INW + ed*524288, nullptr, xz,
                ROWS, 1024, 512, nullptr, 0, 0, 0, flag);
            conv_silu<<<ROWS*DD/256, 256, 0, stream>>>(
                xz, conv_w, ed*1024, conv_b, ed*512, xc, dir ? 1 : -1, flag);
            gemm<<<dim3(1,128), 256, 0, stream>>>(
                xc, xproj_w, ed*64*512, nullptr, proj,
                ROWS, 64, 512, 512, nullptr, 0, 0, 0, 0, flag);
            gemm<<<dim3(8,128), 256, 0, stream>>>(
                proj, dt_w, ed*512*32, nullptr, dtg,
                ROWS, 512, 32, 64, dt_b, ed*512, 1, 0, 0, flag);
            ssm_scan<<<512, 256, 0, stream>>>(
                dtg, xc, proj, xz, A_log, ed*512*16, D_skip, ed*512, dtg, dir, flag);
            // acc += g @ out_w[ed]^T
            gemm_mfma<<<dim3(4,64), 256, 0, stream>>>(
                dtg, wbf + W_OUT + ed*262144, acc, nullptr,
                ROWS, 512, 512, nullptr, 0, 0, 1, flag);
        }
        size_t eo = (size_t)e * 512;
        lnorm<<<2048, 256, 0, stream>>>(nullptr, acc, n1_w, eo, n1_b, eo, x1, 0, flag);
        // ffh = gelu(x1 @ ffn1^T + b1)
        gemm_mfma<<<dim3(16,64), 256, 0, stream>>>(
            x1, wbf + W_FF1 + (size_t)e*1048576, nullptr, ffh,
            ROWS, 2048, 512, ffn1_b, (size_t)e*2048, 2, 0, flag);
        // y2 = ffh @ ffn2^T + b2
        gemm_mfma<<<dim3(4,64), 256, 0, stream>>>(
            ffh, wbf + W_FF2 + (size_t)e*1048576, y2, nullptr,
            ROWS, 512, 2048, ffn2_b, eo, 0, 0, flag);
        lnorm<<<2048, 256, 0, stream>>>(x1, y2, n2_w, eo, n2_b, eo, cur, 0, flag);
    }
    lnorm<<<2048, 256, 0, stream>>>(cur, nullptr, fn_w, 0, fn_b, 0, d_out, 1, flag);
}

// Round 6
// 1341.485 us; speedup vs baseline: 2.7304x; 1.1825x over previous
//
#include <hip/hip_runtime.h>

#define BB 16
#define LL 512
#define DD 512
#define ROWS (BB*LL)   // 8192

typedef unsigned short u16;
typedef __attribute__((ext_vector_type(8))) short short8;
typedef __attribute__((ext_vector_type(4))) float f32x4;

__device__ __forceinline__ float b2f(u16 u) {
    return __uint_as_float(((unsigned int)u) << 16);
}
__device__ __forceinline__ u16 f2b(float f) {
    unsigned int u = __float_as_uint(f);
    u += 0x7FFFu + ((u >> 16) & 1u);
    return (u16)(u >> 16);
}
__device__ __forceinline__ float ld1(const void* p, size_t i, int f32) {
    return f32 ? ((const float*)p)[i] : b2f(((const u16*)p)[i]);
}

// Input dtype detector (fp32 vs bf16), see R2 notes.
__global__ void detect(const u16* __restrict__ x, int* __restrict__ flag)
{
    __shared__ int s;
    if (threadIdx.x == 0) s = 0;
    __syncthreads();
    u16 v = x[2 * threadIdx.x] & 0x7FFFu;
    if ((v & 0x7F80u) >= 0x5000u) atomicOr(&s, 1);
    __syncthreads();
    if (threadIdx.x == 0) *flag = s;
}

// X -> acc (f32) + cur (bf16)
__global__ __launch_bounds__(256)
void cvt_x(const void* __restrict__ X, float* __restrict__ acc, u16* __restrict__ cur,
           const int* __restrict__ flag)
{
    const int f = *flag;
    size_t i = (size_t)blockIdx.x * 256 + threadIdx.x;
    float v = ld1(X, i, f);
    acc[i] = v;
    cur[i] = f2b(v);
}

__global__ __launch_bounds__(256)
void cvt_copy(const void* __restrict__ src, u16* __restrict__ dst, int n,
              const int* __restrict__ flag)
{
    const int f = *flag;
    int i = blockIdx.x * 256 + threadIdx.x;
    if (i < n) dst[i] = f2b(ld1(src, i, f));
}

// XP2 [E][128][1024] block-diag: row r=dir*64+n reads xproj_w[e,dir,n,:] into col half dir.
__global__ __launch_bounds__(256)
void cvt_xp2(const void* __restrict__ xp, u16* __restrict__ dst,
             const int* __restrict__ flag)
{
    const int f = *flag;
    int i = blockIdx.x * 256 + threadIdx.x;   // 0..262143
    int e = i >> 17, r = (i >> 10) & 127, c = i & 1023;
    int dir = r >> 6, n = r & 63;
    float v = ((c >> 9) == dir)
        ? ld1(xp, ((size_t)(e*2 + dir)*64 + n)*512 + (c & 511), f) : 0.f;
    dst[i] = f2b(v);
}

// DT2 [E][1024][128] block-diag: row r=dir*512+d; fwd uses proj cols 0..31, rev 64..95.
__global__ __launch_bounds__(256)
void cvt_dt2(const void* __restrict__ dw, u16* __restrict__ dst,
             const int* __restrict__ flag)
{
    const int f = *flag;
    int i = blockIdx.x * 256 + threadIdx.x;   // 0..262143
    int e = i >> 17, r = (i >> 7) & 1023, c = i & 127;
    int dir = r >> 9, d = r & 511;
    float v = 0.f;
    if (dir == 0 && c < 32)
        v = ld1(dw, ((size_t)(e*2)*512 + d)*32 + c, f);
    else if (dir == 1 && c >= 64 && c < 96)
        v = ld1(dw, ((size_t)(e*2 + 1)*512 + d)*32 + (c - 64), f);
    dst[i] = f2b(v);
}

// OUT2 [E][512][1024] K-concat: row d, col c: out_w[e, c>>9, d, c&511]
__global__ __launch_bounds__(256)
void cvt_out2(const void* __restrict__ ow, u16* __restrict__ dst,
              const int* __restrict__ flag)
{
    const int f = *flag;
    int i = blockIdx.x * 256 + threadIdx.x;   // 0..1048575
    int e = i >> 19, rest = i & 524287;
    int d = rest >> 10, c = rest & 1023;
    int dir = c >> 9;
    dst[i] = f2b(ld1(ow, ((size_t)(e*2 + dir)*512 + d)*512 + (c & 511), f));
}

__global__ __launch_bounds__(256)
void acc_init(const u16* __restrict__ x, float* __restrict__ o)
{
    size_t i = (size_t)blockIdx.x * 256 + threadIdx.x;
    o[i] = b2f(x[i]);
}

// MFMA GEMM: C[M,N] = act(A[M,K] @ W[N,K]^T + bias[boff+c]). A,W bf16 row-major, lda=K.
// 128x128 tile, 4 waves (64x64, 4x4 MFMA grid), BK=32, LDS stride 56.
// accum? Cf+=v : (Cf? Cf=v : Cb=bf16(v)). act:0 none,1 softplus,2 gelu(exact)
__global__ __launch_bounds__(256)
void gemm_mfma(const u16* __restrict__ A, const u16* __restrict__ W,
               float* __restrict__ Cf, u16* __restrict__ Cb,
               int M, int N, int K,
               const void* __restrict__ bias, size_t boff, int act, int accum,
               const int* __restrict__ flag)
{
    const int f = *flag;
    __shared__ u16 As[128][56];
    __shared__ u16 Ws[128][56];
    const int tid  = threadIdx.x;
    const int lane = tid & 63;
    const int wid  = tid >> 6;
    const int wr   = (wid >> 1) * 64;
    const int wc   = (wid & 1) * 64;
    const int row0 = blockIdx.y * 128;
    const int col0 = blockIdx.x * 128;
    const int sr = tid >> 1;
    const int sc = (tid & 1) * 16;
    const int mrow = lane & 15;
    const int kq   = (lane >> 4) * 8;

    f32x4 acc[4][4] = {};
    for (int k0 = 0; k0 < K; k0 += 32) {
        const uint4* ga = (const uint4*)(A + (size_t)(row0 + sr) * K + k0 + sc);
        const uint4* gw = (const uint4*)(W + (size_t)(col0 + sr) * K + k0 + sc);
        uint4 a0 = ga[0], a1 = ga[1];
        uint4 w0 = gw[0], w1 = gw[1];
        *(uint4*)&As[sr][sc]     = a0;
        *(uint4*)&As[sr][sc + 8] = a1;
        *(uint4*)&Ws[sr][sc]     = w0;
        *(uint4*)&Ws[sr][sc + 8] = w1;
        __syncthreads();
        short8 af[4], bf[4];
        #pragma unroll
        for (int mi = 0; mi < 4; ++mi)
            af[mi] = *(const short8*)&As[wr + mi*16 + mrow][kq];
        #pragma unroll
        for (int ni = 0; ni < 4; ++ni)
            bf[ni] = *(const short8*)&Ws[wc + ni*16 + mrow][kq];
        #pragma unroll
        for (int mi = 0; mi < 4; ++mi)
            #pragma unroll
            for (int ni = 0; ni < 4; ++ni)
                acc[mi][ni] = __builtin_amdgcn_mfma_f32_16x16x32_bf16(
                    af[mi], bf[ni], acc[mi][ni], 0, 0, 0);
        __syncthreads();
    }
    const int drow = (lane >> 4) * 4;
    const int dcol = lane & 15;
    #pragma unroll
    for (int mi = 0; mi < 4; ++mi) {
        #pragma unroll
        for (int ni = 0; ni < 4; ++ni) {
            #pragma unroll
            for (int r = 0; r < 4; ++r) {
                int row = row0 + wr + mi*16 + drow + r;
                int col = col0 + wc + ni*16 + dcol;
                float v = acc[mi][ni][r];
                if (bias) v += ld1(bias, boff + col, f);
                if (act == 1) v = (v > 15.f) ? v : log1pf(__expf(v));
                else if (act == 2) v = 0.5f * v * (1.f + erff(v * 0.70710678118f));
                size_t o = (size_t)row * N + col;
                if (accum) Cf[o] += v;
                else if (Cf) Cf[o] = v;
                else Cb[o] = f2b(v);
            }
        }
    }
}

// Both-dirs conv + silu; also rewrites xz z-cols in place as silu(z).
// xz_both [ROWS][2048]: 0..511 x_f | 512..1023 z_f | 1024..1535 x_r | 1536..2047 z_r
__global__ __launch_bounds__(256)
void conv_both(u16* __restrict__ xz, const void* __restrict__ cw,
               const void* __restrict__ cb, u16* __restrict__ xc, int e,
               const int* __restrict__ flag)
{
    const int f = *flag;
    int idx = blockIdx.x * 256 + threadIdx.x;   // ROWS*1024
    int row = idx >> 10;
    int c = idx & 1023;
    int dir = c >> 9, d = c & 511;
    int l = row & (LL - 1);
    size_t base = (size_t)row * 2048 + dir * 1024;
    float xcur = b2f(xz[base + d]);
    int dsign = dir ? 1 : -1;
    int ln = l + dsign;
    float xnb = (ln >= 0 && ln < LL) ? b2f(xz[base + dsign*2048 + d]) : 0.f;
    size_t co = (size_t)(e*2 + dir) * 1024 + 2*d;
    float v = ld1(cw, co, f) * xnb + ld1(cw, co + 1, f) * xcur
            + ld1(cb, (size_t)(e*2 + dir)*512 + d, f);
    xc[(size_t)row * 1024 + c] = f2b(v / (1.f + __expf(-v)));
    float z = b2f(xz[base + 512 + d]);
    xz[base + 512 + d] = f2b(z / (1.f + __expf(-z)));
}

// Both-dirs selective scan, 8-step register-prefetch. 1024 blocks.
// g overwrites dt column in dtg_both (read precedes write per chunk; same (row,col)).
__global__ __launch_bounds__(256)
void ssm_scan(u16* __restrict__ dtg, const u16* __restrict__ xc,
              const u16* __restrict__ proj, const u16* __restrict__ xz,
              const void* __restrict__ A_log, const void* __restrict__ Dsk, int e,
              const int* __restrict__ flag)
{
    const int f = *flag;
    int lane = threadIdx.x & 15;
    int gg = blockIdx.x * 16 + (threadIdx.x >> 4);   // 0..16383
    int dir = gg >> 13;
    int rem = gg & 8191;
    int b = rem >> 9, d = rem & 511;
    int ed = e*2 + dir;
    float Av = -__expf(ld1(A_log, (size_t)ed*8192 + d*16 + lane, f));
    float Dv = ld1(Dsk, (size_t)ed*512 + d, f);
    int col  = dir*512 + d;
    int zcol = dir*1024 + 512 + d;
    int pcol = dir*64 + 32 + lane;
    float h = 0.f;
    size_t rb = (size_t)b * LL;
    for (int s0 = 0; s0 < LL; s0 += 8) {
        float dtv[8], xv[8], Bn[8], Cn[8], zs[8];
        #pragma unroll
        for (int j = 0; j < 8; ++j) {
            int l = dir ? (LL - 1 - (s0 + j)) : (s0 + j);
            size_t row = rb + l;
            dtv[j] = b2f(dtg[row*1024 + col]);
            xv[j]  = b2f(xc[row*1024 + col]);
            Bn[j]  = b2f(proj[row*128 + pcol]);
            Cn[j]  = b2f(proj[row*128 + pcol + 16]);
            zs[j]  = b2f(xz[row*2048 + zcol]);   // pre-silu'd
        }
        #pragma unroll
        for (int j = 0; j < 8; ++j) {
            int l = dir ? (LL - 1 - (s0 + j)) : (s0 + j);
            size_t row = rb + l;
            h = __expf(dtv[j] * Av) * h + dtv[j] * Bn[j] * xv[j];
            float c = h * Cn[j];
            c += __shfl_xor(c, 8);
            c += __shfl_xor(c, 4);
            c += __shfl_xor(c, 2);
            c += __shfl_xor(c, 1);
            if (lane == 0)
                dtg[row*1024 + col] = f2b((c + Dv * xv[j]) * zs[j]);
        }
    }
}

__global__ __launch_bounds__(256)
void lnorm(const u16* __restrict__ Xb, const float* __restrict__ Xf,
           const void* __restrict__ w, size_t wo, const void* __restrict__ b, size_t bo,
           void* __restrict__ out, int omode, const int* __restrict__ flag)
{
    const int f = *flag;
    int wid = (blockIdx.x * 256 + threadIdx.x) >> 6;
    int lane = threadIdx.x & 63;
    size_t base = (size_t)wid * DD;
    float v[8];
    float s = 0.f;
    #pragma unroll
    for (int i = 0; i < 8; ++i) {
        int c = lane + i*64;
        float t = 0.f;
        if (Xb) t += b2f(Xb[base + c]);
        if (Xf) t += Xf[base + c];
        v[i] = t; s += t;
    }
    #pragma unroll
    for (int off = 32; off > 0; off >>= 1) s += __shfl_xor(s, off);
    float mean = s * (1.f/512.f);
    float var = 0.f;
    #pragma unroll
    for (int i = 0; i < 8; ++i) { float dlt = v[i] - mean; var += dlt*dlt; }
    #pragma unroll
    for (int off = 32; off > 0; off >>= 1) var += __shfl_xor(var, off);
    float rstd = rsqrtf(var * (1.f/512.f) + 1e-5f);
    #pragma unroll
    for (int i = 0; i < 8; ++i) {
        int c = lane + i*64;
        float o = (v[i] - mean) * rstd * ld1(w, wo + c, f) + ld1(b, bo + c, f);
        if (omode && f) ((float*)out)[base + c] = o;
        else            ((u16*)out)[base + c] = f2b(o);
    }
}

extern "C" void kernel_launch(void* const* d_in, const int* in_sizes, int n_in,
                              void* d_out, int out_size, void* d_ws, size_t ws_size,
                              hipStream_t stream)
{
    (void)in_sizes; (void)n_in; (void)out_size; (void)ws_size;
    const void* X       = d_in[0];
    const void* in_w    = d_in[1];
    const void* conv_w  = d_in[2];
    const void* conv_b  = d_in[3];
    const void* xproj_w = d_in[4];
    const void* dt_w    = d_in[5];
    const void* dt_b    = d_in[6];
    const void* A_log   = d_in[7];
    const void* D_skip  = d_in[8];
    const void* out_w   = d_in[9];
    const void* ffn1_w  = d_in[10];
    const void* ffn1_b  = d_in[11];
    const void* ffn2_w  = d_in[12];
    const void* ffn2_b  = d_in[13];
    const void* n1_w    = d_in[14];
    const void* n1_b    = d_in[15];
    const void* n2_w    = d_in[16];
    const void* n2_b    = d_in[17];
    const void* fn_w    = d_in[18];
    const void* fn_b    = d_in[19];

    // Workspace (~105 MB):
    // acc f32 @0 (16M) | cur bf16 @16M (8M) | xz_both @24M (32M; ffn: ffh)
    // xc_both @56M (16M; ffn: y2 f32) | dtg_both @72M (16M; ffn: x1 first 8M)
    // proj_both @88M (2M) | flag @90M | wbf @90M+4K (15M)
    char* p = (char*)d_ws;
    float* acc  = (float*)(p);
    u16*   cur  = (u16*)(p + 16777216);
    u16*   xz   = (u16*)(p + 25165824);
    u16*   xc   = (u16*)(p + 58720256);
    u16*   dtg  = (u16*)(p + 75497472);
    u16*   proj = (u16*)(p + 92274688);
    int*   flag = (int*)(p + 94371840);
    u16*   wbf  = (u16*)(p + 94375936);
    u16*   ffh  = xz;
    float* y2   = (float*)xc;
    u16*   x1   = dtg;
    // wbf element offsets
    const size_t W_IN  = 0;        // in_w copy           2,097,152
    const size_t W_XP  = 2097152;  // XP2 block-diag        262,144
    const size_t W_DT  = 2359296;  // DT2 block-diag        262,144
    const size_t W_OUT = 2621440;  // OUT2 K-concat       1,048,576
    const size_t W_FF1 = 3670016;  // ffn1 copy           2,097,152
    const size_t W_FF2 = 5767168;  // ffn2 copy           2,097,152

    detect<<<1, 512, 0, stream>>>((const u16*)X, flag);
    cvt_x<<<ROWS*DD/256, 256, 0, stream>>>(X, acc, cur, flag);
    cvt_copy<<<2097152/256, 256, 0, stream>>>(in_w,   wbf + W_IN,  2097152, flag);
    cvt_copy<<<2097152/256, 256, 0, stream>>>(ffn1_w, wbf + W_FF1, 2097152, flag);
    cvt_copy<<<2097152/256, 256, 0, stream>>>(ffn2_w, wbf + W_FF2, 2097152, flag);
    cvt_xp2<<<262144/256, 256, 0, stream>>>(xproj_w, wbf + W_XP, flag);
    cvt_dt2<<<262144/256, 256, 0, stream>>>(dt_w, wbf + W_DT, flag);
    cvt_out2<<<1048576/256, 256, 0, stream>>>(out_w, wbf + W_OUT, flag);

    for (int e = 0; e < 2; ++e) {
        if (e == 1)
            acc_init<<<ROWS*DD/256, 256, 0, stream>>>(cur, acc);
        // xz_both = cur @ [in_f; in_r]^T : [8192,2048]
        gemm_mfma<<<dim3(16,64), 256, 0, stream>>>(
            cur, wbf + W_IN + (size_t)e*1048576, nullptr, xz,
            ROWS, 2048, 512, nullptr, 0, 0, 0, flag);
        conv_both<<<ROWS*1024/256, 256, 0, stream>>>(xz, conv_w, conv_b, xc, e, flag);
        // proj_both = xc_both @ XP2^T : [8192,128]
        gemm_mfma<<<dim3(1,64), 256, 0, stream>>>(
            xc, wbf + W_XP + (size_t)e*131072, nullptr, proj,
            ROWS, 128, 1024, nullptr, 0, 0, 0, flag);
        // dt_both = softplus(proj_both @ DT2^T + dt_b) : [8192,1024]
        gemm_mfma<<<dim3(8,64), 256, 0, stream>>>(
            proj, wbf + W_DT + (size_t)e*131072, nullptr, dtg,
            ROWS, 1024, 128, dt_b, (size_t)e*1024, 1, 0, flag);
        ssm_scan<<<1024, 256, 0, stream>>>(dtg, xc, proj, xz, A_log, D_skip, e, flag);
        // acc += g_both @ OUT2^T : [8192,512]
        gemm_mfma<<<dim3(4,64), 256, 0, stream>>>(
            dtg, wbf + W_OUT + (size_t)e*524288, acc, nullptr,
            ROWS, 512, 1024, nullptr, 0, 0, 1, flag);
        size_t eo = (size_t)e * 512;
        lnorm<<<2048, 256, 0, stream>>>(nullptr, acc, n1_w, eo, n1_b, eo, x1, 0, flag);
        gemm_mfma<<<dim3(16,64), 256, 0, stream>>>(
            x1, wbf + W_FF1 + (size_t)e*1048576, nullptr, ffh,
            ROWS, 2048, 512, ffn1_b, (size_t)e*2048, 2, 0, flag);
        gemm_mfma<<<dim3(4,64), 256, 0, stream>>>(
            ffh, wbf + W_FF2 + (size_t)e*1048576, y2, nullptr,
            ROWS, 512, 2048, ffn2_b, eo, 0, 0, flag);
        lnorm<<<2048, 256, 0, stream>>>(x1, y2, n2_w, eo, n2_b, eo, cur, 0, flag);
    }
    lnorm<<<2048, 256, 0, stream>>>(cur, nullptr, fn_w, 0, fn_b, 0, d_out, 1, flag);
}